// Round 4
// baseline (486.858 us; speedup 1.0000x reference)
//
#include <hip/hip_runtime.h>
#include <stdint.h>

#define O_FEATS 28672
#define I_FEATS 8192
#define BATCH 8
#define WPR 2048  // packed int32 words per output row (I/4); only low byte used

// ---------------------------------------------------------------------------
// Workspace layout (uint32 word indices into ws):
//   ws[0]        : final absmax (float bits, >= 1e-5), written by k_quant
//   ws[16..79]   : per-block absmax partials (64 blocks of k_absmax)
//   ws[128..191] : per-block sum_x partials, index = b*8 + seg
//   ws[1024..]   : x_q int8 [8][8192] (64 KB)
// ---------------------------------------------------------------------------

#if __has_builtin(__builtin_amdgcn_sdot4)
#define DOT4(a, b, c) __builtin_amdgcn_sdot4((a), (b), (c), false)
#else
static __device__ __forceinline__ int dot4_sw(int a, int b, int c) {
  c += (int)(signed char)(a & 0xff) * (int)(signed char)(b & 0xff);
  c += (int)(signed char)((a >> 8) & 0xff) * (int)(signed char)((b >> 8) & 0xff);
  c += (int)(signed char)((a >> 16) & 0xff) * (int)(signed char)((b >> 16) & 0xff);
  c += (int)(signed char)((a >> 24) & 0xff) * (int)(signed char)((b >> 24) & 0xff);
  return c;
}
#define DOT4(a, b, c) dot4_sw((a), (b), (c))
#endif

// Carry-free unpack of 4 ternary codes (bits [7:0] of p) to 4 unsigned bytes.
static __device__ __forceinline__ int unpack4(uint32_t p) {
  uint32_t lo = p & 0x0Fu;
  uint32_t hi = (p >> 4) & 0x0Fu;
  uint32_t a = (lo * 0x41u) & 0x0303u;
  uint32_t b = (hi * 0x41u) & 0x0303u;
  return (int)(a | (b << 16));
}

// 64 blocks x 256 threads x 4 floats = 65536 elements; per-block partial max.
__global__ void k_absmax(const float* __restrict__ x, uint32_t* __restrict__ ws) {
  __shared__ float red[4];
  int t = threadIdx.x;
  float4 v = ((const float4*)x)[blockIdx.x * 256 + t];
  float m = fmaxf(fmaxf(fabsf(v.x), fabsf(v.y)), fmaxf(fabsf(v.z), fabsf(v.w)));
#pragma unroll
  for (int off = 32; off; off >>= 1)
    m = fmaxf(m, __shfl_xor(m, off));
  if ((t & 63) == 0) red[t >> 6] = m;
  __syncthreads();
  if (t == 0)
    ws[16 + blockIdx.x] =
        __float_as_uint(fmaxf(fmaxf(red[0], red[1]), fmaxf(red[2], red[3])));
}

// 64 blocks: block (b = blk>>3, seg = blk&7) quantizes 1024 elems of row b.
__global__ void k_quant(const float* __restrict__ x, uint32_t* __restrict__ ws) {
  __shared__ float s_amax;
  __shared__ int reds[4];
  int b = blockIdx.x >> 3, seg = blockIdx.x & 7;
  int t = threadIdx.x;
  if (t < 64) {  // reduce the 64 absmax partials (all blocks redundantly)
    float m = __uint_as_float(ws[16 + t]);
#pragma unroll
    for (int off = 32; off; off >>= 1)
      m = fmaxf(m, __shfl_xor(m, off));
    if (t == 0) {
      float a = fmaxf(m, 1e-5f);
      s_amax = a;
      ws[0] = __float_as_uint(a);  // same value from every block: benign
    }
  }
  __syncthreads();
  float s = s_amax / 127.0f;  // match ref: x / (absmax/127)
  float4 v = ((const float4*)(x + b * I_FEATS + seg * 1024))[t];
  int q0 = (int)fminf(fmaxf(rintf(v.x / s), -128.f), 127.f);
  int q1 = (int)fminf(fmaxf(rintf(v.y / s), -128.f), 127.f);
  int q2 = (int)fminf(fmaxf(rintf(v.z / s), -128.f), 127.f);
  int q3 = (int)fminf(fmaxf(rintf(v.w / s), -128.f), 127.f);
  uint32_t pk = (uint32_t)(q0 & 0xff) | ((uint32_t)(q1 & 0xff) << 8) |
                ((uint32_t)(q2 & 0xff) << 16) | ((uint32_t)(q3 & 0xff) << 24);
  ws[1024 + b * 2048 + seg * 256 + t] = pk;
  int s4 = q0 + q1 + q2 + q3;
#pragma unroll
  for (int off = 32; off; off >>= 1)
    s4 += __shfl_xor(s4, off);
  if ((t & 63) == 0) reds[t >> 6] = s4;
  __syncthreads();
  if (t == 0)
    ws[128 + blockIdx.x] = (uint32_t)(reds[0] + reds[1] + reds[2] + reds[3]);
}

// GEMM: 7168 blocks x 256 thr; block -> 4 output rows, K split across
// waves and lanes. Wave w, lane l, half kk owns words
// base = kk*1024 + w*256 + 4*l of each row (16 weights, one int4 load).
// x_q for that chunk lives in 32 VGPRs (8 batches x int4) -- no x LDS.
__global__ void __launch_bounds__(256, 4)
k_gemm(const int* __restrict__ Wp, const float* __restrict__ wscale,
       const float* __restrict__ bias, const uint32_t* __restrict__ ws,
       float* __restrict__ out) {
  __shared__ int red[4][32];
  __shared__ int s_sumx[BATCH];
  __shared__ float s_scale;

  const int t = threadIdx.x;
  const int wave = t >> 6, lane = t & 63;

  if (t < 64) {  // reduce 64 sum_x partials: index = b*8+seg
    int p = (int)ws[128 + t];
    p += __shfl_xor(p, 1);
    p += __shfl_xor(p, 2);
    p += __shfl_xor(p, 4);
    if ((t & 7) == 0) s_sumx[t >> 3] = p;
    if (t == 0) s_scale = (__uint_as_float(ws[0]) / 127.0f) * wscale[0];
  }

  const int o0 = blockIdx.x * 4;
  const uint32_t* xq = ws + 1024;
  const int boff = wave * 256 + 4 * lane;  // word offset within a K-half

  // weight loads for BOTH K-halves up front: 8 int4 in flight per lane
  int4 wv[2][4];
#pragma unroll
  for (int kk = 0; kk < 2; ++kk)
#pragma unroll
    for (int oo = 0; oo < 4; ++oo)
      wv[kk][oo] = *(const int4*)(Wp + (o0 + oo) * WPR + kk * 1024 + boff);

  int acc[4][8];
#pragma unroll
  for (int oo = 0; oo < 4; ++oo)
#pragma unroll
    for (int b = 0; b < 8; ++b) acc[oo][b] = 0;

#pragma unroll
  for (int kk = 0; kk < 2; ++kk) {
    const int base = kk * 1024 + boff;
    int4 xv[8];
#pragma unroll
    for (int b = 0; b < 8; ++b)
      xv[b] = *(const int4*)(xq + b * 2048 + base);
#pragma unroll
    for (int oo = 0; oo < 4; ++oo) {
      const uint32_t* pw = (const uint32_t*)&wv[kk][oo];
      const int c0 = unpack4(pw[0]);
      const int c1 = unpack4(pw[1]);
      const int c2 = unpack4(pw[2]);
      const int c3 = unpack4(pw[3]);
#pragma unroll
      for (int b = 0; b < 8; ++b) {
        acc[oo][b] = DOT4(c0, xv[b].x, acc[oo][b]);
        acc[oo][b] = DOT4(c1, xv[b].y, acc[oo][b]);
        acc[oo][b] = DOT4(c2, xv[b].z, acc[oo][b]);
        acc[oo][b] = DOT4(c3, xv[b].w, acc[oo][b]);
      }
    }
  }

  // In-wave split-butterfly: 32 partials/lane over 64 lanes in 32 shuffles.
  // After 5 steps lane L's v[0] holds value h = bitrev5(L&31) for its
  // 32-lane half; xor-32 finishes. All static indices (no scratch).
  int v[32];
#pragma unroll
  for (int oo = 0; oo < 4; ++oo)
#pragma unroll
    for (int b = 0; b < 8; ++b) v[oo * 8 + b] = acc[oo][b];
#pragma unroll
  for (int s = 0; s < 5; ++s) {
    const int m = 1 << s;
    const int n = 16 >> s;
    const bool up = (lane & m) != 0;
#pragma unroll
    for (int i = 0; i < n; ++i) {
      int give = up ? v[i] : v[i + n];
      int keep = up ? v[i + n] : v[i];
      v[i] = keep + __shfl_xor(give, m);
    }
  }
  int tot = v[0] + __shfl_xor(v[0], 32);

  if (lane < 32) {
    int h = ((lane & 1) << 4) | ((lane & 2) << 2) | (lane & 4) |
            ((lane & 8) >> 2) | ((lane & 16) >> 4);
    red[wave][h] = tot;  // h is a permutation of 0..31: conflict-free
  }
  __syncthreads();

  if (t < 32) {
    int s = red[0][t] + red[1][t] + red[2][t] + red[3][t];
    int oo = t >> 3, b = t & 7;
    int o = o0 + oo;
    out[b * O_FEATS + o] = (float)(s - s_sumx[b]) * s_scale + bias[o];
  }
}

extern "C" void kernel_launch(void* const* d_in, const int* in_sizes, int n_in,
                              void* d_out, int out_size, void* d_ws, size_t ws_size,
                              hipStream_t stream) {
  const float* x = (const float*)d_in[0];
  const int* pw = (const int*)d_in[1];
  const float* wscale = (const float*)d_in[2];
  const float* bias = (const float*)d_in[3];
  float* out = (float*)d_out;
  uint32_t* ws = (uint32_t*)d_ws;

  k_absmax<<<64, 256, 0, stream>>>(x, ws);
  k_quant<<<64, 256, 0, stream>>>(x, ws);
  k_gemm<<<O_FEATS / 4, 256, 0, stream>>>(pw, wscale, bias, ws, out);
}

// Round 5
// 344.420 us; speedup vs baseline: 1.4136x; 1.4136x over previous
//
#include <hip/hip_runtime.h>
#include <stdint.h>

#define O_FEATS 28672
#define I_FEATS 8192
#define BATCH 8
#define WPR 2048  // packed int32 words per output row (I/4); only low byte used

typedef int i32x4 __attribute__((ext_vector_type(4)));

// ---------------------------------------------------------------------------
// Workspace layout (uint32 word indices into ws):
//   ws[0]        : final absmax (float bits, >= 1e-5), written by k_quant
//   ws[16..79]   : per-block absmax partials (64 blocks of k_absmax)
//   ws[128..191] : per-block sum_x partials, index = b*8 + seg
//   ws[1024..]   : x_q int8 [16][8192] (128 KB; rows 8..15 zeroed)
// ---------------------------------------------------------------------------

// Carry-free unpack of 4 ternary codes (bits [7:0] of p) to 4 unsigned bytes
// {c0,c1,c2,c3} at byte positions 0..3 == k-offsets 0..3 of that word.
static __device__ __forceinline__ int unpack4(uint32_t p) {
  uint32_t lo = p & 0x0Fu;
  uint32_t hi = (p >> 4) & 0x0Fu;
  uint32_t a = (lo * 0x41u) & 0x0303u;
  uint32_t b = (hi * 0x41u) & 0x0303u;
  return (int)(a | (b << 16));
}

// 64 blocks x 256 threads x 4 floats = 65536 elements; per-block partial max.
__global__ void k_absmax(const float* __restrict__ x, uint32_t* __restrict__ ws) {
  __shared__ float red[4];
  int t = threadIdx.x;
  float4 v = ((const float4*)x)[blockIdx.x * 256 + t];
  float m = fmaxf(fmaxf(fabsf(v.x), fabsf(v.y)), fmaxf(fabsf(v.z), fabsf(v.w)));
#pragma unroll
  for (int off = 32; off; off >>= 1)
    m = fmaxf(m, __shfl_xor(m, off));
  if ((t & 63) == 0) red[t >> 6] = m;
  __syncthreads();
  if (t == 0)
    ws[16 + blockIdx.x] =
        __float_as_uint(fmaxf(fmaxf(red[0], red[1]), fmaxf(red[2], red[3])));
}

// 128 blocks. Blocks 0..63: (b = blk>>3, seg = blk&7) quantize 1024 elems of
// row b + partial sums. Blocks 64..127: zero-fill pad rows 8..15.
__global__ void k_quant(const float* __restrict__ x, uint32_t* __restrict__ ws) {
  __shared__ float s_amax;
  __shared__ int reds[4];
  int t = threadIdx.x;
  if (blockIdx.x >= 64) {  // zero rows 8..15 of x_q (A-operand M-padding)
    int row = 8 + ((blockIdx.x - 64) >> 3), seg = blockIdx.x & 7;
    ws[1024 + row * 2048 + seg * 256 + t] = 0u;
    return;
  }
  int b = blockIdx.x >> 3, seg = blockIdx.x & 7;
  if (t < 64) {  // reduce the 64 absmax partials (redundantly per block)
    float m = __uint_as_float(ws[16 + t]);
#pragma unroll
    for (int off = 32; off; off >>= 1)
      m = fmaxf(m, __shfl_xor(m, off));
    if (t == 0) {
      float a = fmaxf(m, 1e-5f);
      s_amax = a;
      ws[0] = __float_as_uint(a);  // same value from every block: benign
    }
  }
  __syncthreads();
  float s = s_amax / 127.0f;  // match ref: x / (absmax/127)
  float4 v = ((const float4*)(x + b * I_FEATS + seg * 1024))[t];
  int q0 = (int)fminf(fmaxf(rintf(v.x / s), -128.f), 127.f);
  int q1 = (int)fminf(fmaxf(rintf(v.y / s), -128.f), 127.f);
  int q2 = (int)fminf(fmaxf(rintf(v.z / s), -128.f), 127.f);
  int q3 = (int)fminf(fmaxf(rintf(v.w / s), -128.f), 127.f);
  uint32_t pk = (uint32_t)(q0 & 0xff) | ((uint32_t)(q1 & 0xff) << 8) |
                ((uint32_t)(q2 & 0xff) << 16) | ((uint32_t)(q3 & 0xff) << 24);
  ws[1024 + b * 2048 + seg * 256 + t] = pk;
  int s4 = q0 + q1 + q2 + q3;
#pragma unroll
  for (int off = 32; off; off >>= 1)
    s4 += __shfl_xor(s4, off);
  if ((t & 63) == 0) reds[t >> 6] = s4;
  __syncthreads();
  if (t == 0)
    ws[128 + blockIdx.x] = (uint32_t)(reds[0] + reds[1] + reds[2] + reds[3]);
}

// MFMA GEMM: 896 blocks x 256 thr. Block -> 2 tiles of 16 output rows;
// wave w -> tile (blk*2 + (w>>1)), K-half (w&1). Per K-step (K=64):
//   B-frag: lane reads int4 = 4 packed words of row o_base+(lane&15) at
//           k = k0 + (lane>>4)*16 .. +15; unpack4(word r) == frag reg r.
//   A-frag: lane reads int4 of x_q row (lane&15) same k-window (L2-hot).
//   acc += mfma_i32_16x16x64_i8(A, B)  -- matrix pipe, VALU only unpacks.
// D layout: col(=output) = lane&15, row(=batch) = (lane>>4)*4 + reg.
__global__ void __launch_bounds__(256, 4)
k_gemm(const int* __restrict__ Wp, const float* __restrict__ wscale,
       const float* __restrict__ bias, const uint32_t* __restrict__ ws,
       float* __restrict__ out) {
  __shared__ int red[4][32][4];
  __shared__ int s_sumx[BATCH];
  __shared__ float s_scale;

  const int t = threadIdx.x;
  const int wave = t >> 6, lane = t & 63;

  if (t < 64) {  // reduce 64 sum_x partials: index = b*8+seg
    int p = (int)ws[128 + t];
    p += __shfl_xor(p, 1);
    p += __shfl_xor(p, 2);
    p += __shfl_xor(p, 4);
    if ((t & 7) == 0) s_sumx[t >> 3] = p;
    if (t == 0) s_scale = (__uint_as_float(ws[0]) / 127.0f) * wscale[0];
  }

  const int tile = blockIdx.x * 2 + (wave >> 1);
  const int khalf = wave & 1;
  const int o_base = tile * 16;
  const int m = lane & 15, g = lane >> 4;

  const uint8_t* xq8 = (const uint8_t*)(ws + 1024);
  // both streams advance 64 bytes per K-step (64 int8 x / 16 packed words w)
  const int4* ap = (const int4*)(xq8 + m * 8192 + khalf * 4096 + g * 16);
  const int4* wp =
      (const int4*)((const uint8_t*)Wp + (o_base + m) * 8192 + khalf * 4096 + g * 16);

  i32x4 acc = {0, 0, 0, 0};
  int4 a0 = ap[0], b0 = wp[0];
#pragma unroll 4
  for (int s = 0; s < 64; ++s) {
    int4 a1, b1;
    if (s < 63) {  // 1-ahead prefetch
      a1 = ap[(s + 1) * 4];
      b1 = wp[(s + 1) * 4];
    }
    i32x4 af, bf;
    af.x = a0.x; af.y = a0.y; af.z = a0.z; af.w = a0.w;
    bf.x = unpack4((uint32_t)b0.x);
    bf.y = unpack4((uint32_t)b0.y);
    bf.z = unpack4((uint32_t)b0.z);
    bf.w = unpack4((uint32_t)b0.w);
    acc = __builtin_amdgcn_mfma_i32_16x16x64_i8(af, bf, acc, 0, 0, 0);
    a0 = a1;
    b0 = b1;
  }

  if (lane < 32) {  // rows 0..7 live in lanes 0..31 (row = (lane>>4)*4+reg)
#pragma unroll
    for (int r = 0; r < 4; ++r) red[wave][lane][r] = acc[r];
  }
  __syncthreads();

  if (khalf == 0 && lane < 32) {  // combine K-halves, epilogue, store
    const int n = lane & 15;
    const int q = lane >> 4;
    const int o = o_base + n;
    const float bo = bias[o];
#pragma unroll
    for (int r = 0; r < 4; ++r) {
      int mm = q * 4 + r;  // batch row 0..7
      int tot = red[wave][lane][r] + red[wave + 1][lane][r];
      out[mm * O_FEATS + o] = (float)(tot - s_sumx[mm]) * s_scale + bo;
    }
  }
}

extern "C" void kernel_launch(void* const* d_in, const int* in_sizes, int n_in,
                              void* d_out, int out_size, void* d_ws, size_t ws_size,
                              hipStream_t stream) {
  const float* x = (const float*)d_in[0];
  const int* pw = (const int*)d_in[1];
  const float* wscale = (const float*)d_in[2];
  const float* bias = (const float*)d_in[3];
  float* out = (float*)d_out;
  uint32_t* ws = (uint32_t*)d_ws;

  k_absmax<<<64, 256, 0, stream>>>(x, ws);
  k_quant<<<128, 256, 0, stream>>>(x, ws);
  k_gemm<<<O_FEATS / 32, 256, 0, stream>>>(pw, wscale, bias, ws, out);
}

// Round 6
// 334.172 us; speedup vs baseline: 1.4569x; 1.0307x over previous
//
#include <hip/hip_runtime.h>
#include <stdint.h>

#define O_FEATS 28672
#define I_FEATS 8192
#define BATCH 8

typedef int i32x4 __attribute__((ext_vector_type(4)));

// ---------------------------------------------------------------------------
// Workspace layout (uint32 word indices into ws):
//   ws[0]        : final absmax (float bits, >= 1e-5), written by k_quant
//   ws[16..79]   : per-block absmax partials (64 blocks of k_absmax)
//   ws[128..191] : per-block sum_x partials, index = b*8 + seg
//   ws[1024..]   : x_q int8 [16][8192] (128 KB; rows 8..15 zeroed)
// ---------------------------------------------------------------------------

// Carry-free unpack of 4 ternary codes (bits [7:0] of p) to 4 unsigned bytes
// {c0,c1,c2,c3} at byte positions 0..3 == k-offsets 0..3 of that word.
static __device__ __forceinline__ int unpack4(uint32_t p) {
  uint32_t lo = p & 0x0Fu;
  uint32_t hi = (p >> 4) & 0x0Fu;
  uint32_t a = (lo * 0x41u) & 0x0303u;
  uint32_t b = (hi * 0x41u) & 0x0303u;
  return (int)(a | (b << 16));
}

// 64 blocks x 256 threads x 4 floats = 65536 elements; per-block partial max.
__global__ void k_absmax(const float* __restrict__ x, uint32_t* __restrict__ ws) {
  __shared__ float red[4];
  int t = threadIdx.x;
  float4 v = ((const float4*)x)[blockIdx.x * 256 + t];
  float m = fmaxf(fmaxf(fabsf(v.x), fabsf(v.y)), fmaxf(fabsf(v.z), fabsf(v.w)));
#pragma unroll
  for (int off = 32; off; off >>= 1)
    m = fmaxf(m, __shfl_xor(m, off));
  if ((t & 63) == 0) red[t >> 6] = m;
  __syncthreads();
  if (t == 0)
    ws[16 + blockIdx.x] =
        __float_as_uint(fmaxf(fmaxf(red[0], red[1]), fmaxf(red[2], red[3])));
}

// 128 blocks. Blocks 0..63: (b = blk>>3, seg = blk&7) quantize 1024 elems of
// row b + partial sums. Blocks 64..127: zero-fill pad rows 8..15.
__global__ void k_quant(const float* __restrict__ x, uint32_t* __restrict__ ws) {
  __shared__ float s_amax;
  __shared__ int reds[4];
  int t = threadIdx.x;
  if (blockIdx.x >= 64) {  // zero rows 8..15 of x_q (A-operand M-padding)
    int row = 8 + ((blockIdx.x - 64) >> 3), seg = blockIdx.x & 7;
    ws[1024 + row * 2048 + seg * 256 + t] = 0u;
    return;
  }
  int b = blockIdx.x >> 3, seg = blockIdx.x & 7;
  if (t < 64) {  // reduce the 64 absmax partials (redundantly per block)
    float m = __uint_as_float(ws[16 + t]);
#pragma unroll
    for (int off = 32; off; off >>= 1)
      m = fmaxf(m, __shfl_xor(m, off));
    if (t == 0) {
      float a = fmaxf(m, 1e-5f);
      s_amax = a;
      ws[0] = __float_as_uint(a);  // same value from every block: benign
    }
  }
  __syncthreads();
  float s = s_amax / 127.0f;  // match ref: x / (absmax/127)
  float4 v = ((const float4*)(x + b * I_FEATS + seg * 1024))[t];
  int q0 = (int)fminf(fmaxf(rintf(v.x / s), -128.f), 127.f);
  int q1 = (int)fminf(fmaxf(rintf(v.y / s), -128.f), 127.f);
  int q2 = (int)fminf(fmaxf(rintf(v.z / s), -128.f), 127.f);
  int q3 = (int)fminf(fmaxf(rintf(v.w / s), -128.f), 127.f);
  uint32_t pk = (uint32_t)(q0 & 0xff) | ((uint32_t)(q1 & 0xff) << 8) |
                ((uint32_t)(q2 & 0xff) << 16) | ((uint32_t)(q3 & 0xff) << 24);
  ws[1024 + b * 2048 + seg * 256 + t] = pk;
  int s4 = q0 + q1 + q2 + q3;
#pragma unroll
  for (int off = 32; off; off >>= 1)
    s4 += __shfl_xor(s4, off);
  if ((t & 63) == 0) reds[t >> 6] = s4;
  __syncthreads();
  if (t == 0)
    ws[128 + blockIdx.x] = (uint32_t)(reds[0] + reds[1] + reds[2] + reds[3]);
}

// MFMA GEMM: 1792 blocks x 256 thr = 7 blocks/CU exactly (28 waves/CU).
// Block -> one tile of 16 output rows; wave w -> K-quarter w (32 steps of
// K=64). Per K-step:
//   B-frag: lane reads int4 = 4 packed words of row o_base+(lane&15) at
//           k-window (lane>>4); unpack4(word r) == frag reg r.
//   A-frag: lane reads int4 of x_q row (lane&15), same k-window (L2-hot).
//   acc += mfma_i32_16x16x64_i8(A, B).
// 4-deep register ring, fully unrolled: 8 loads in flight/wave, all offsets
// static (step stride 64 B; 31*64 < 4 KB fits the 13-bit signed offset).
// D layout: col(=output) = lane&15, row(=batch) = (lane>>4)*4 + reg.
__global__ void __launch_bounds__(256, 7)
k_gemm(const int* __restrict__ Wp, const float* __restrict__ wscale,
       const float* __restrict__ bias, const uint32_t* __restrict__ ws,
       float* __restrict__ out) {
  __shared__ int red[4][32][4];
  __shared__ int s_sumx[BATCH];
  __shared__ float s_scale;

  const int t = threadIdx.x;
  const int wave = t >> 6, lane = t & 63;

  if (t < 64) {  // reduce 64 sum_x partials: index = b*8+seg
    int p = (int)ws[128 + t];
    p += __shfl_xor(p, 1);
    p += __shfl_xor(p, 2);
    p += __shfl_xor(p, 4);
    if ((t & 7) == 0) s_sumx[t >> 3] = p;
    if (t == 0) s_scale = (__uint_as_float(ws[0]) / 127.0f) * wscale[0];
  }

  const int o_base = blockIdx.x * 16;
  const int m = lane & 15, g = lane >> 4;

  // wave w owns k bytes [w*2048, (w+1)*2048) of every row; step stride 64 B
  const uint8_t* xq8 = (const uint8_t*)(ws + 1024);
  const int4* ap = (const int4*)(xq8 + m * 8192 + wave * 2048 + g * 16);
  const int4* wp = (const int4*)((const uint8_t*)Wp + (size_t)(o_base + m) * 8192 +
                                 wave * 2048 + g * 16);

  i32x4 acc = {0, 0, 0, 0};
  int4 abuf[4], bbuf[4];
#pragma unroll
  for (int i = 0; i < 4; ++i) {
    abuf[i] = ap[i * 4];
    bbuf[i] = wp[i * 4];
  }
#pragma unroll
  for (int s = 0; s < 32; ++s) {
    int4 a = abuf[s & 3];
    int4 b = bbuf[s & 3];
    if (s + 4 < 32) {  // static after full unroll
      abuf[s & 3] = ap[(s + 4) * 4];
      bbuf[s & 3] = wp[(s + 4) * 4];
    }
    i32x4 af, bf;
    af.x = a.x; af.y = a.y; af.z = a.z; af.w = a.w;
    bf.x = unpack4((uint32_t)b.x);
    bf.y = unpack4((uint32_t)b.y);
    bf.z = unpack4((uint32_t)b.z);
    bf.w = unpack4((uint32_t)b.w);
    acc = __builtin_amdgcn_mfma_i32_16x16x64_i8(af, bf, acc, 0, 0, 0);
  }

  if (lane < 32) {  // batch rows 0..7 live in lanes 0..31
#pragma unroll
    for (int r = 0; r < 4; ++r) red[wave][lane][r] = acc[r];
  }
  __syncthreads();

  if (t < 32) {  // combine 4 K-quarters, epilogue, store
    const int n = t & 15;
    const int q = t >> 4;
    const int o = o_base + n;
    const float bo = bias[o];
#pragma unroll
    for (int r = 0; r < 4; ++r) {
      int mm = q * 4 + r;  // batch row 0..7
      int tot = red[0][t][r] + red[1][t][r] + red[2][t][r] + red[3][t][r];
      out[mm * O_FEATS + o] = (float)(tot - s_sumx[mm]) * s_scale + bo;
    }
  }
}

extern "C" void kernel_launch(void* const* d_in, const int* in_sizes, int n_in,
                              void* d_out, int out_size, void* d_ws, size_t ws_size,
                              hipStream_t stream) {
  const float* x = (const float*)d_in[0];
  const int* pw = (const int*)d_in[1];
  const float* wscale = (const float*)d_in[2];
  const float* bias = (const float*)d_in[3];
  float* out = (float*)d_out;
  uint32_t* ws = (uint32_t*)d_ws;

  k_absmax<<<64, 256, 0, stream>>>(x, ws);
  k_quant<<<128, 256, 0, stream>>>(x, ws);
  k_gemm<<<O_FEATS / 16, 256, 0, stream>>>(pw, wscale, bias, ws, out);
}

// Round 7
// 327.779 us; speedup vs baseline: 1.4853x; 1.0195x over previous
//
#include <hip/hip_runtime.h>
#include <stdint.h>

#define O_FEATS 28672
#define I_FEATS 8192
#define BATCH 8

typedef int i32x4 __attribute__((ext_vector_type(4)));

// ---------------------------------------------------------------------------
// Workspace layout (uint32 word indices into ws):
//   ws[0]        : final absmax (float bits, >= 1e-5), written by k_quant
//   ws[16..79]   : per-block absmax partials (64 blocks of k_absmax)
//   ws[128..191] : per-block sum_x partials, index = b*8 + seg
//   ws[1024..]   : x_q TRANSPOSED to MFMA-fragment order, 128 KB:
//                  T[S*1024 + L*16 + j] = x_q[row L&15][k=S*64+(L>>4)*16+j]
//                  (S = global K-step 0..127, L = lane 0..63; rows 8..15 = 0)
// ---------------------------------------------------------------------------

// Carry-free unpack of 4 ternary codes (bits [7:0] of p) to 4 unsigned bytes
// {c0,c1,c2,c3} at byte positions 0..3 == k-offsets 0..3 of that word.
static __device__ __forceinline__ int unpack4(uint32_t p) {
  uint32_t lo = p & 0x0Fu;
  uint32_t hi = (p >> 4) & 0x0Fu;
  uint32_t a = (lo * 0x41u) & 0x0303u;
  uint32_t b = (hi * 0x41u) & 0x0303u;
  return (int)(a | (b << 16));
}

// 64 blocks x 256 threads x 4 floats = 65536 elements; per-block partial max.
__global__ void k_absmax(const float* __restrict__ x, uint32_t* __restrict__ ws) {
  __shared__ float red[4];
  int t = threadIdx.x;
  float4 v = ((const float4*)x)[blockIdx.x * 256 + t];
  float m = fmaxf(fmaxf(fabsf(v.x), fabsf(v.y)), fmaxf(fabsf(v.z), fabsf(v.w)));
#pragma unroll
  for (int off = 32; off; off >>= 1)
    m = fmaxf(m, __shfl_xor(m, off));
  if ((t & 63) == 0) red[t >> 6] = m;
  __syncthreads();
  if (t == 0)
    ws[16 + blockIdx.x] =
        __float_as_uint(fmaxf(fmaxf(red[0], red[1]), fmaxf(red[2], red[3])));
}

// 128 blocks. Blocks 0..63: (b = blk>>3, seg = blk&7) quantize 1024 elems of
// row b, write into transposed layout T + partial sums. Blocks 64..127:
// zero-fill pad rows 8..15 of T.
__global__ void k_quant(const float* __restrict__ x, uint32_t* __restrict__ ws) {
  __shared__ float s_amax;
  __shared__ int reds[4];
  int t = threadIdx.x;
  if (blockIdx.x >= 64) {  // zero pad rows 8..15 in T
    int row = 8 + ((blockIdx.x - 64) >> 3), seg = blockIdx.x & 7;
    int k0 = seg * 1024 + t * 4;
    int S = k0 >> 6, g = (k0 >> 4) & 3, j = k0 & 15;
    ws[1024 + ((S * 1024 + (g * 16 + row) * 16 + j) >> 2)] = 0u;
    return;
  }
  int b = blockIdx.x >> 3, seg = blockIdx.x & 7;
  if (t < 64) {  // reduce the 64 absmax partials (redundantly per block)
    float m = __uint_as_float(ws[16 + t]);
#pragma unroll
    for (int off = 32; off; off >>= 1)
      m = fmaxf(m, __shfl_xor(m, off));
    if (t == 0) {
      float a = fmaxf(m, 1e-5f);
      s_amax = a;
      ws[0] = __float_as_uint(a);  // same value from every block: benign
    }
  }
  __syncthreads();
  float s = s_amax / 127.0f;  // match ref: x / (absmax/127)
  float4 v = ((const float4*)(x + b * I_FEATS + seg * 1024))[t];
  int q0 = (int)fminf(fmaxf(rintf(v.x / s), -128.f), 127.f);
  int q1 = (int)fminf(fmaxf(rintf(v.y / s), -128.f), 127.f);
  int q2 = (int)fminf(fmaxf(rintf(v.z / s), -128.f), 127.f);
  int q3 = (int)fminf(fmaxf(rintf(v.w / s), -128.f), 127.f);
  uint32_t pk = (uint32_t)(q0 & 0xff) | ((uint32_t)(q1 & 0xff) << 8) |
                ((uint32_t)(q2 & 0xff) << 16) | ((uint32_t)(q3 & 0xff) << 24);
  {  // scatter into transposed fragment layout (4 B words, aligned)
    int k0 = seg * 1024 + t * 4;
    int S = k0 >> 6, g = (k0 >> 4) & 3, j = k0 & 15;
    ws[1024 + ((S * 1024 + (g * 16 + b) * 16 + j) >> 2)] = pk;
  }
  int s4 = q0 + q1 + q2 + q3;
#pragma unroll
  for (int off = 32; off; off >>= 1)
    s4 += __shfl_xor(s4, off);
  if ((t & 63) == 0) reds[t >> 6] = s4;
  __syncthreads();
  if (t == 0)
    ws[128 + blockIdx.x] = (uint32_t)(reds[0] + reds[1] + reds[2] + reds[3]);
}

// MFMA GEMM: 1792 blocks x 256 thr. Block -> one tile of 16 output rows;
// wave w -> K-quarter w (32 steps of K=64). Per K-step:
//   A-frag: ONE coalesced 1KB wave-load from transposed x_q (L1/L2-hot):
//           addr = T + S*1024 + lane*16  (S = wave*32 + s).
//   B-frag: lane reads int4 = 4 packed words of row o_base+(lane&15) at
//           k-window (lane>>4); unpack4(word r) == frag reg r.
//   acc += mfma_i32_16x16x64_i8(A, B).
// 4-deep register ring, fully unrolled, all offsets static.
// D layout: col(=output) = lane&15, row(=batch) = (lane>>4)*4 + reg.
__global__ void __launch_bounds__(256, 4)
k_gemm(const int* __restrict__ Wp, const float* __restrict__ wscale,
       const float* __restrict__ bias, const uint32_t* __restrict__ ws,
       float* __restrict__ out) {
  __shared__ int red[4][32][4];
  __shared__ int s_sumx[BATCH];
  __shared__ float s_scale;

  const int t = threadIdx.x;
  const int wave = t >> 6, lane = t & 63;

  if (t < 64) {  // reduce 64 sum_x partials: index = b*8+seg
    int p = (int)ws[128 + t];
    p += __shfl_xor(p, 1);
    p += __shfl_xor(p, 2);
    p += __shfl_xor(p, 4);
    if ((t & 7) == 0) s_sumx[t >> 3] = p;
    if (t == 0) s_scale = (__uint_as_float(ws[0]) / 127.0f) * wscale[0];
  }

  const int o_base = blockIdx.x * 16;
  const int m = lane & 15, g = lane >> 4;

  // A: transposed x_q, coalesced; step stride 1024 B (= 64 int4)
  const uint8_t* xqT = (const uint8_t*)(ws + 1024);
  const int4* ap = (const int4*)(xqT + (size_t)(wave * 32) * 1024 + lane * 16);
  // B: weight rows, fragment-scattered (16 x 64 B per instr); stride 64 B
  const int4* wp = (const int4*)((const uint8_t*)Wp + (size_t)(o_base + m) * 8192 +
                                 wave * 2048 + g * 16);

  i32x4 acc = {0, 0, 0, 0};
  int4 abuf[4], bbuf[4];
#pragma unroll
  for (int i = 0; i < 4; ++i) {
    abuf[i] = ap[i * 64];
    bbuf[i] = wp[i * 4];
  }
#pragma unroll
  for (int s = 0; s < 32; ++s) {
    int4 a = abuf[s & 3];
    int4 b = bbuf[s & 3];
    if (s + 4 < 32) {  // static after full unroll
      abuf[s & 3] = ap[(s + 4) * 64];
      bbuf[s & 3] = wp[(s + 4) * 4];
    }
    i32x4 af, bf;
    af.x = a.x; af.y = a.y; af.z = a.z; af.w = a.w;
    bf.x = unpack4((uint32_t)b.x);
    bf.y = unpack4((uint32_t)b.y);
    bf.z = unpack4((uint32_t)b.z);
    bf.w = unpack4((uint32_t)b.w);
    acc = __builtin_amdgcn_mfma_i32_16x16x64_i8(af, bf, acc, 0, 0, 0);
  }

  if (lane < 32) {  // batch rows 0..7 live in lanes 0..31
#pragma unroll
    for (int r = 0; r < 4; ++r) red[wave][lane][r] = acc[r];
  }
  __syncthreads();

  if (t < 32) {  // combine 4 K-quarters, epilogue, store
    const int n = t & 15;
    const int q = t >> 4;
    const int o = o_base + n;
    const float bo = bias[o];
#pragma unroll
    for (int r = 0; r < 4; ++r) {
      int mm = q * 4 + r;  // batch row 0..7
      int tot = red[0][t][r] + red[1][t][r] + red[2][t][r] + red[3][t][r];
      out[mm * O_FEATS + o] = (float)(tot - s_sumx[mm]) * s_scale + bo;
    }
  }
}

extern "C" void kernel_launch(void* const* d_in, const int* in_sizes, int n_in,
                              void* d_out, int out_size, void* d_ws, size_t ws_size,
                              hipStream_t stream) {
  const float* x = (const float*)d_in[0];
  const int* pw = (const int*)d_in[1];
  const float* wscale = (const float*)d_in[2];
  const float* bias = (const float*)d_in[3];
  float* out = (float*)d_out;
  uint32_t* ws = (uint32_t*)d_ws;

  k_absmax<<<64, 256, 0, stream>>>(x, ws);
  k_quant<<<128, 256, 0, stream>>>(x, ws);
  k_gemm<<<O_FEATS / 16, 256, 0, stream>>>(pw, wscale, bias, ws, out);
}

// Round 8
// 320.853 us; speedup vs baseline: 1.5174x; 1.0216x over previous
//
#include <hip/hip_runtime.h>
#include <stdint.h>

#define O_FEATS 28672
#define I_FEATS 8192
#define BATCH 8
#define PITCH_W 260  // LDS words per W row: 1024 B data + 16 B pad

typedef int i32x4 __attribute__((ext_vector_type(4)));

// ---------------------------------------------------------------------------
// Workspace layout (uint32 word indices into ws):
//   ws[0]        : final absmax (float bits, >= 1e-5), written by k_quant
//   ws[16..79]   : per-block absmax partials (64 blocks of k_absmax)
//   ws[128..191] : per-block sum_x partials, index = b*8 + seg
//   ws[1024..]   : x_q TRANSPOSED to MFMA-fragment order, 128 KB:
//                  T[S*1024 + L*16 + j] = x_q[row L&15][k=S*64+(L>>4)*16+j]
//                  (S = global K-step 0..127, L = lane 0..63; rows 8..15 = 0)
// ---------------------------------------------------------------------------

// Carry-free unpack of 4 ternary codes (bits [7:0] of p) to 4 unsigned bytes
// {c0,c1,c2,c3} at byte positions 0..3 == k-offsets 0..3 of that word.
static __device__ __forceinline__ int unpack4(uint32_t p) {
  uint32_t lo = p & 0x0Fu;
  uint32_t hi = (p >> 4) & 0x0Fu;
  uint32_t a = (lo * 0x41u) & 0x0303u;
  uint32_t b = (hi * 0x41u) & 0x0303u;
  return (int)(a | (b << 16));
}

// 64 blocks x 256 threads x 4 floats = 65536 elements; per-block partial max.
__global__ void k_absmax(const float* __restrict__ x, uint32_t* __restrict__ ws) {
  __shared__ float red[4];
  int t = threadIdx.x;
  float4 v = ((const float4*)x)[blockIdx.x * 256 + t];
  float m = fmaxf(fmaxf(fabsf(v.x), fabsf(v.y)), fmaxf(fabsf(v.z), fabsf(v.w)));
#pragma unroll
  for (int off = 32; off; off >>= 1)
    m = fmaxf(m, __shfl_xor(m, off));
  if ((t & 63) == 0) red[t >> 6] = m;
  __syncthreads();
  if (t == 0)
    ws[16 + blockIdx.x] =
        __float_as_uint(fmaxf(fmaxf(red[0], red[1]), fmaxf(red[2], red[3])));
}

// 128 blocks. Blocks 0..63: (b = blk>>3, seg = blk&7) quantize 1024 elems of
// row b, write into transposed layout T + partial sums. Blocks 64..127:
// zero-fill pad rows 8..15 of T.
__global__ void k_quant(const float* __restrict__ x, uint32_t* __restrict__ ws) {
  __shared__ float s_amax;
  __shared__ int reds[4];
  int t = threadIdx.x;
  if (blockIdx.x >= 64) {  // zero pad rows 8..15 in T
    int row = 8 + ((blockIdx.x - 64) >> 3), seg = blockIdx.x & 7;
    int k0 = seg * 1024 + t * 4;
    int S = k0 >> 6, g = (k0 >> 4) & 3, j = k0 & 15;
    ws[1024 + ((S * 1024 + (g * 16 + row) * 16 + j) >> 2)] = 0u;
    return;
  }
  int b = blockIdx.x >> 3, seg = blockIdx.x & 7;
  if (t < 64) {  // reduce the 64 absmax partials (redundantly per block)
    float m = __uint_as_float(ws[16 + t]);
#pragma unroll
    for (int off = 32; off; off >>= 1)
      m = fmaxf(m, __shfl_xor(m, off));
    if (t == 0) {
      float a = fmaxf(m, 1e-5f);
      s_amax = a;
      ws[0] = __float_as_uint(a);  // same value from every block: benign
    }
  }
  __syncthreads();
  float s = s_amax / 127.0f;  // match ref: x / (absmax/127)
  float4 v = ((const float4*)(x + b * I_FEATS + seg * 1024))[t];
  int q0 = (int)fminf(fmaxf(rintf(v.x / s), -128.f), 127.f);
  int q1 = (int)fminf(fmaxf(rintf(v.y / s), -128.f), 127.f);
  int q2 = (int)fminf(fmaxf(rintf(v.z / s), -128.f), 127.f);
  int q3 = (int)fminf(fmaxf(rintf(v.w / s), -128.f), 127.f);
  uint32_t pk = (uint32_t)(q0 & 0xff) | ((uint32_t)(q1 & 0xff) << 8) |
                ((uint32_t)(q2 & 0xff) << 16) | ((uint32_t)(q3 & 0xff) << 24);
  {  // scatter into transposed fragment layout (4 B words, aligned)
    int k0 = seg * 1024 + t * 4;
    int S = k0 >> 6, g = (k0 >> 4) & 3, j = k0 & 15;
    ws[1024 + ((S * 1024 + (g * 16 + b) * 16 + j) >> 2)] = pk;
  }
  int s4 = q0 + q1 + q2 + q3;
#pragma unroll
  for (int off = 32; off; off >>= 1)
    s4 += __shfl_xor(s4, off);
  if ((t & 63) == 0) reds[t >> 6] = s4;
  __syncthreads();
  if (t == 0)
    ws[128 + blockIdx.x] = (uint32_t)(reds[0] + reds[1] + reds[2] + reds[3]);
}

// MFMA GEMM, LDS-staged weights: 1792 blocks x 256 thr (7 blocks/CU).
// Block -> 16 output rows. K processed in 8 chunks of 1024 B/row:
//   stage : wave w async-copies rows w*4..w*4+3 (1 KB contiguous each) via
//           global_load_lds (16 B/lane, wave-uniform LDS base -> m104-safe).
//   compute: within chunk, wave w owns k-sub [w*256,(w+1)*256) = 4 steps of
//           K=64. B-frag = ds_read_b128 at row (lane&15), byte
//           w*256+s*64+(lane>>4)*16; unpack4(word r) == frag reg r (as R5-R7).
//           A-frag = one coalesced 1 KB wave-load from transposed x_q at
//           step S = c*16+w*4+s (identical k-window to B by construction).
// D layout: col(=output) = lane&15, row(=batch) = (lane>>4)*4 + reg.
__global__ void __launch_bounds__(256, 4)
k_gemm(const int* __restrict__ Wp, const float* __restrict__ wscale,
       const float* __restrict__ bias, const uint32_t* __restrict__ ws,
       float* __restrict__ out) {
  __shared__ uint32_t Wlds[16 * PITCH_W];  // 16.6 KB staged W chunk
  __shared__ int red[4][32][4];
  __shared__ int s_sumx[BATCH];
  __shared__ float s_scale;

  const int t = threadIdx.x;
  const int wave = t >> 6, lane = t & 63;

  if (t < 64) {  // reduce 64 sum_x partials: index = b*8+seg
    int p = (int)ws[128 + t];
    p += __shfl_xor(p, 1);
    p += __shfl_xor(p, 2);
    p += __shfl_xor(p, 4);
    if ((t & 7) == 0) s_sumx[t >> 3] = p;
    if (t == 0) s_scale = (__uint_as_float(ws[0]) / 127.0f) * wscale[0];
  }

  const int o_base = blockIdx.x * 16;
  const int m = lane & 15, g = lane >> 4;

  // A: transposed x_q; step S = c*16 + wave*4 + s; wave*4 folded into base.
  const uint8_t* xqT = (const uint8_t*)(ws + 1024);
  const int4* ap = (const int4*)(xqT + (size_t)(wave * 4) * 1024 + lane * 16);

  // B staging source: rows (o_base + wave*4 + i), chunk offset c*1024.
  const uint8_t* src_base =
      (const uint8_t*)Wp + (size_t)(o_base + wave * 4) * 8192 + lane * 16;
  uint32_t* lds_row0 = &Wlds[(wave * 4) * PITCH_W];

  // B fragment read address (constant across chunks)
  const uint32_t* bp0 = &Wlds[m * PITCH_W + (wave * 256 + g * 16) / 4];

  i32x4 acc = {0, 0, 0, 0};

  for (int c = 0; c < 8; ++c) {
    __syncthreads();  // previous chunk fully consumed
#pragma unroll
    for (int i = 0; i < 4; ++i) {  // async stage 4 rows x 1 KB -> LDS
      const uint32_t* src = (const uint32_t*)(src_base + (size_t)i * 8192 + c * 1024);
      __builtin_amdgcn_global_load_lds(src, lds_row0 + i * PITCH_W, 16, 0, 0);
    }
    int4 a[4];
#pragma unroll
    for (int s = 0; s < 4; ++s) a[s] = ap[(c * 16 + s) * 64];
    __syncthreads();  // barrier drains vmcnt -> staged LDS visible to all
#pragma unroll
    for (int s = 0; s < 4; ++s) {
      int4 b = *(const int4*)(bp0 + s * 16);
      i32x4 af, bf;
      af.x = a[s].x; af.y = a[s].y; af.z = a[s].z; af.w = a[s].w;
      bf.x = unpack4((uint32_t)b.x);
      bf.y = unpack4((uint32_t)b.y);
      bf.z = unpack4((uint32_t)b.z);
      bf.w = unpack4((uint32_t)b.w);
      acc = __builtin_amdgcn_mfma_i32_16x16x64_i8(af, bf, acc, 0, 0, 0);
    }
  }

  if (lane < 32) {  // batch rows 0..7 live in lanes 0..31
#pragma unroll
    for (int r = 0; r < 4; ++r) red[wave][lane][r] = acc[r];
  }
  __syncthreads();

  if (t < 32) {  // combine 4 wave-partials (disjoint K), epilogue, store
    const int n = t & 15;
    const int q = t >> 4;
    const int o = o_base + n;
    const float bo = bias[o];
#pragma unroll
    for (int r = 0; r < 4; ++r) {
      int mm = q * 4 + r;  // batch row 0..7
      int tot = red[0][t][r] + red[1][t][r] + red[2][t][r] + red[3][t][r];
      out[mm * O_FEATS + o] = (float)(tot - s_sumx[mm]) * s_scale + bo;
    }
  }
}

extern "C" void kernel_launch(void* const* d_in, const int* in_sizes, int n_in,
                              void* d_out, int out_size, void* d_ws, size_t ws_size,
                              hipStream_t stream) {
  const float* x = (const float*)d_in[0];
  const int* pw = (const int*)d_in[1];
  const float* wscale = (const float*)d_in[2];
  const float* bias = (const float*)d_in[3];
  float* out = (float*)d_out;
  uint32_t* ws = (uint32_t*)d_ws;

  k_absmax<<<64, 256, 0, stream>>>(x, ws);
  k_quant<<<128, 256, 0, stream>>>(x, ws);
  k_gemm<<<O_FEATS / 16, 256, 0, stream>>>(pw, wscale, bias, ws, out);
}